// Round 8
// baseline (85.568 us; speedup 1.0000x reference)
//
#include <hip/hip_runtime.h>
#include <hip/hip_bf16.h>

#define NN 50000      // nodes
#define EE 800000     // edges
#define KD 512        // IN_DIM
#define ND 256        // H*D

typedef __bf16 bf16x8 __attribute__((ext_vector_type(8)));
typedef float f32x4 __attribute__((ext_vector_type(4)));

// fire-and-forget 16B global->LDS copy (dest = wave-uniform base + lane*16)
#define GLD16(g, l) __builtin_amdgcn_global_load_lds( \
    (const __attribute__((address_space(1))) unsigned int*)(g), \
    (__attribute__((address_space(3))) unsigned int*)(l), 16, 0, 0)

// ---------- Kernel 1: fused  (a) W (512x256 f32) -> Wt (256x512 bf16 [n][k])
//                             (b) zero the flags array ----------
// prep's plain zero-stores become device-coherent at its end-of-kernel
// release (L2 writeback) -- required before gemm's AGENT-scope flag writes.
__global__ __launch_bounds__(256) void prep_kernel(const float* __restrict__ W,
                                                   __hip_bfloat16* __restrict__ Wt,
                                                   unsigned char* __restrict__ flags) {
    if (blockIdx.x >= 32) {
        int idx = (blockIdx.x - 32) * 256 + threadIdx.x;
        if (idx < 3125) reinterpret_cast<uint4*>(flags)[idx] = (uint4){0, 0, 0, 0};
        return;
    }
    __shared__ __align__(16) __hip_bfloat16 tile[64][72];
    const int bk = blockIdx.x & 7;
    const int bn = blockIdx.x >> 3;
    const int k0 = bk * 64, n0 = bn * 64;
    const int t = threadIdx.x;
    const int r = t >> 2;
    const int c = (t & 3) * 16;
    const float4* src = reinterpret_cast<const float4*>(W + (size_t)(k0 + r) * ND + n0 + c);
#pragma unroll
    for (int i = 0; i < 4; ++i) {
        float4 f = src[i];
        tile[c + i * 4 + 0][r] = __float2bfloat16(f.x);
        tile[c + i * 4 + 1][r] = __float2bfloat16(f.y);
        tile[c + i * 4 + 2][r] = __float2bfloat16(f.z);
        tile[c + i * 4 + 3][r] = __float2bfloat16(f.w);
    }
    __syncthreads();
    uint4* dst = reinterpret_cast<uint4*>(Wt + (size_t)(n0 + r) * KD + k0 + c);
    dst[0] = *reinterpret_cast<const uint4*>(&tile[r][c]);
    dst[1] = *reinterpret_cast<const uint4*>(&tile[r][c + 8]);
}

__device__ __forceinline__ bf16x8 cvt8(f32x4 lo, f32x4 hi) {
    union { __hip_bfloat16 h[8]; bf16x8 v; } u;
    u.h[0] = __float2bfloat16(lo[0]); u.h[1] = __float2bfloat16(lo[1]);
    u.h[2] = __float2bfloat16(lo[2]); u.h[3] = __float2bfloat16(lo[3]);
    u.h[4] = __float2bfloat16(hi[0]); u.h[5] = __float2bfloat16(hi[1]);
    u.h[6] = __float2bfloat16(hi[2]); u.h[7] = __float2bfloat16(hi[3]);
    return u.v;
}

// ---------- Kernel 2: fused edge-flag phase + masked GEMM ----------
// GEMM core is R7-verbatim (equal-best; at delivered-byte ceiling ~6.5 TB/s).
// NEW: flag_set folded into the gemm PROLOGUE. Safety argument:
//  - all 391 blocks are co-resident from t=0 (LDS 53 KB -> 2/CU = 512 slots,
//    VGPR 64), so every block's edge phase (~first few us) completes >=15 us
//    before the earliest epilogue (main loop is ~30 us of staged streaming);
//  - cross-XCD visibility: edge writes are __hip_atomic_store AGENT scope
//    (bypass non-coherent XCD L2 to the coherent point); epilogue reads are
//    __hip_atomic_load AGENT scope; prep's zeros were made coherent by its
//    kernel-end release. No inter-block ordering beyond the timing margin.
__global__ __launch_bounds__(512, 4) void gemm_mask_kernel(const float* __restrict__ x,
                                                           const __hip_bfloat16* __restrict__ Wt,
                                                           const int* __restrict__ dst_idx,
                                                           unsigned char* __restrict__ flags,
                                                           float* __restrict__ out) {
    __shared__ __align__(16) char As[2][10240];   // 128 rows x 80 B (64 data + 16 pad), bf16
    __shared__ __align__(16) char Bs[2][16384];

    const int t = threadIdx.x;

    // ---- edge phase: blind AGENT-scope flag stores for this block's slice ----
    {
        int base = blockIdx.x * 2048 + t * 4;
        if (base < EE) {   // EE%4==0, base%4==0 -> base+3 < EE
            int4 d = *reinterpret_cast<const int4*>(dst_idx + base);
            __hip_atomic_store(&flags[d.x], (unsigned char)1, __ATOMIC_RELAXED, __HIP_MEMORY_SCOPE_AGENT);
            __hip_atomic_store(&flags[d.y], (unsigned char)1, __ATOMIC_RELAXED, __HIP_MEMORY_SCOPE_AGENT);
            __hip_atomic_store(&flags[d.z], (unsigned char)1, __ATOMIC_RELAXED, __HIP_MEMORY_SCOPE_AGENT);
            __hip_atomic_store(&flags[d.w], (unsigned char)1, __ATOMIC_RELAXED, __HIP_MEMORY_SCOPE_AGENT);
        }
    }

    const int w = t >> 6;             // wave 0..7
    const int l = t & 63;
    const int wm = w >> 2;            // 0..1  (M half)
    const int wn = w & 3;             // 0..3  (N quarter)
    const int m_base = blockIdx.x * 128;

    // ---- A staging: thread -> row ar = t>>2 (0..127), quarter q = t&3 ----
    const int ar = t >> 2;
    const int q = t & 3;
    const char* aSrcR;
    {
        int m = m_base + ar; if (m > NN - 1) m = NN - 1;   // clamp (stores guarded)
        aSrcR = (const char*)x + (size_t)m * (KD * 4) + q * 32;
    }
    const int aWr = ar * 80 + q * 16;  // LDS byte dest for this thread's 8 bf16

    // ---- B staging sources (per-lane, inverse-swizzled; verified R5/R7) ----
    const char* bSrc[2];
#pragma unroll
    for (int j = 0; j < 2; ++j) {
        int o = j * 8192 + w * 1024 + l * 16;
        int br = o >> 7;
        int g = ((o >> 4) & 7) ^ (br & 7);
        int n = 2 * br + (g >> 2);
        bSrc[j] = (const char*)Wt + (size_t)n * (KD * 2) + (g & 3) * 16;
    }

    // ---- consume-side offsets ----
    const int fr = l & 15;            // fragment row within 16
    const int fo = l >> 4;            // k sub-block 0..3
    const int aOff = (wm * 64 + fr) * 80 + fo * 16;
    const int bOff = (wn * 32 + (fr >> 1)) * 128 +
                     (((fr & 1) * 64 + fo * 16) ^ (((fr >> 1) & 7) << 4));

    f32x4 acc[4][4];
#pragma unroll
    for (int i = 0; i < 4; ++i)
#pragma unroll
        for (int j = 0; j < 4; ++j) acc[i][j] = (f32x4){0.f, 0.f, 0.f, 0.f};

    f32x4 ga[2][2];   // gA reg slots; slot kt&1 holds step kt's f32 data

#define LOAD_GA(kt)                                                              \
    {                                                                            \
        ga[(kt) & 1][0] = *reinterpret_cast<const f32x4*>(aSrcR + (kt) * 128);   \
        ga[(kt) & 1][1] = *reinterpret_cast<const f32x4*>(aSrcR + (kt) * 128 + 16); \
    }
#define STAGE_B(kt)                                                  \
    {                                                                \
        GLD16(bSrc[0] + (kt) * 64, &Bs[(kt) & 1][w * 1024]);         \
        GLD16(bSrc[1] + (kt) * 64, &Bs[(kt) & 1][8192 + w * 1024]);  \
    }
#define WRITE_A(kt)                                                  \
    *reinterpret_cast<bf16x8*>(&As[(kt) & 1][aWr]) =                 \
        cvt8(ga[(kt) & 1][0], ga[(kt) & 1][1]);

    // ---- prologue: queue = [edge stores...][gA(0) x2][B(0) x2][gA(1) x2] ----
    // NOTE: edge-phase stores are older vmcnt entries; waits below are counted
    // from the most recent loads, so include the store count conservatively by
    // draining once before the pipeline starts.
    asm volatile("s_waitcnt vmcnt(0)" ::: "memory");   // edge stores + idx load retired
    LOAD_GA(0);
    __builtin_amdgcn_sched_barrier(0);
    STAGE_B(0);
    __builtin_amdgcn_sched_barrier(0);
    LOAD_GA(1);
    __builtin_amdgcn_sched_barrier(0);
    asm volatile("s_waitcnt vmcnt(4)" ::: "memory");   // gA(0) landed
    WRITE_A(0);

#pragma unroll
    for (int kt = 0; kt < 16; ++kt) {
        const int cur = kt & 1;
        if (kt < 15) {
            asm volatile("s_waitcnt vmcnt(2) lgkmcnt(0)" ::: "memory");
        } else {
            asm volatile("s_waitcnt vmcnt(0) lgkmcnt(0)" ::: "memory");
        }
        __builtin_amdgcn_s_barrier();      // LDS A(kt), B(kt) globally ready
        __builtin_amdgcn_sched_barrier(0);

        if (kt < 15) STAGE_B(kt + 1);
        __builtin_amdgcn_sched_barrier(0);
        if (kt < 14) LOAD_GA(kt + 2);
        __builtin_amdgcn_sched_barrier(0);

        bf16x8 bfr[4];
#pragma unroll
        for (int tn = 0; tn < 4; ++tn)
            bfr[tn] = *reinterpret_cast<const bf16x8*>(&Bs[cur][bOff + tn * 1024]);
#pragma unroll
        for (int h = 0; h < 2; ++h) {
            bf16x8 afr[2];
#pragma unroll
            for (int u = 0; u < 2; ++u)
                afr[u] = *reinterpret_cast<const bf16x8*>(&As[cur][aOff + (h * 2 + u) * 1280]);
#pragma unroll
            for (int u = 0; u < 2; ++u)
#pragma unroll
                for (int tn = 0; tn < 4; ++tn)
                    acc[h * 2 + u][tn] = __builtin_amdgcn_mfma_f32_16x16x32_bf16(afr[u], bfr[tn], acc[h * 2 + u][tn], 0, 0, 0);
        }

        if (kt < 14) {
            asm volatile("s_waitcnt vmcnt(4)" ::: "memory");
            WRITE_A(kt + 1);
        } else if (kt == 14) {
            asm volatile("s_waitcnt vmcnt(2)" ::: "memory");
            WRITE_A(15);
        }
    }
#undef LOAD_GA
#undef STAGE_B
#undef WRITE_A

    // ---- epilogue: C/D layout col=lane&15, row=(lane>>4)*4+r ----
    // flags read at AGENT scope (coherent point) -- written by all blocks'
    // edge phases, which completed >=15 us ago (co-residency margin).
    const int col = l & 15;
    const int rq = (l >> 4) * 4;
#pragma unroll
    for (int tm = 0; tm < 4; ++tm) {
#pragma unroll
        for (int r = 0; r < 4; ++r) {
            const int m = m_base + wm * 64 + tm * 16 + rq + r;
            if (m < NN) {
                const float fl = (float)__hip_atomic_load(&flags[m], __ATOMIC_RELAXED, __HIP_MEMORY_SCOPE_AGENT);
                float* orow = out + (size_t)m * ND + wn * 64 + col;
#pragma unroll
                for (int tn = 0; tn < 4; ++tn)
                    orow[tn * 16] = acc[tm][tn][r] * fl;
            }
        }
    }
}

extern "C" void kernel_launch(void* const* d_in, const int* in_sizes, int n_in,
                              void* d_out, int out_size, void* d_ws, size_t ws_size,
                              hipStream_t stream) {
    const float* x = (const float*)d_in[0];          // (N, 512) f32
    const int* edge_index = (const int*)d_in[1];     // (2, E) i32: row0=src, row1=dst
    const float* W = (const float*)d_in[3];          // (512, 256) f32
    float* out = (float*)d_out;                      // (N, 256) f32

    unsigned char* flags = (unsigned char*)d_ws;                       // NN bytes (16B-aligned)
    __hip_bfloat16* Wt = (__hip_bfloat16*)((char*)d_ws + 65536);       // 256 KB

    prep_kernel<<<45, 256, 0, stream>>>(W, Wt, flags);
    gemm_mask_kernel<<<(NN + 127) / 128, 512, 0, stream>>>(x, Wt, edge_index + EE, flags, out);
}

// Round 9
// 48.001 us; speedup vs baseline: 1.7826x; 1.7826x over previous
//
#include <hip/hip_runtime.h>
#include <hip/hip_bf16.h>

#define NN 50000      // nodes
#define EE 800000     // edges
#define KD 512        // IN_DIM
#define ND 256        // H*D

typedef __bf16 bf16x8 __attribute__((ext_vector_type(8)));
typedef float f32x4 __attribute__((ext_vector_type(4)));

// fire-and-forget 16B global->LDS copy (dest = wave-uniform base + lane*16)
#define GLD16(g, l) __builtin_amdgcn_global_load_lds( \
    (const __attribute__((address_space(1))) unsigned int*)(g), \
    (__attribute__((address_space(3))) unsigned int*)(l), 16, 0, 0)

// ---------- Kernel 1: fused  (a) W (512x256 f32) -> Wt (256x512 bf16 [n][k])
//                             (b) zero the flags array ----------
__global__ __launch_bounds__(256) void prep_kernel(const float* __restrict__ W,
                                                   __hip_bfloat16* __restrict__ Wt,
                                                   unsigned char* __restrict__ flags) {
    if (blockIdx.x >= 32) {
        int idx = (blockIdx.x - 32) * 256 + threadIdx.x;
        if (idx < 3125) reinterpret_cast<uint4*>(flags)[idx] = (uint4){0, 0, 0, 0};
        return;
    }
    __shared__ __align__(16) __hip_bfloat16 tile[64][72];
    const int bk = blockIdx.x & 7;
    const int bn = blockIdx.x >> 3;
    const int k0 = bk * 64, n0 = bn * 64;
    const int t = threadIdx.x;
    const int r = t >> 2;
    const int c = (t & 3) * 16;
    const float4* src = reinterpret_cast<const float4*>(W + (size_t)(k0 + r) * ND + n0 + c);
#pragma unroll
    for (int i = 0; i < 4; ++i) {
        float4 f = src[i];
        tile[c + i * 4 + 0][r] = __float2bfloat16(f.x);
        tile[c + i * 4 + 1][r] = __float2bfloat16(f.y);
        tile[c + i * 4 + 2][r] = __float2bfloat16(f.z);
        tile[c + i * 4 + 3][r] = __float2bfloat16(f.w);
    }
    __syncthreads();
    uint4* dst = reinterpret_cast<uint4*>(Wt + (size_t)(n0 + r) * KD + k0 + c);
    dst[0] = *reinterpret_cast<const uint4*>(&tile[r][c]);
    dst[1] = *reinterpret_cast<const uint4*>(&tile[r][c + 8]);
}

// ---------- Kernel 2: flags[dst[e]] = 1 via test-and-set ----------
__global__ __launch_bounds__(256) void flag_set_kernel(const int* __restrict__ dst_idx,
                                                       unsigned char* __restrict__ flags) {
    int i = (blockIdx.x * 256 + threadIdx.x) * 4;
    if (i >= EE) return;  // EE % 4 == 0
    int4 d = *reinterpret_cast<const int4*>(dst_idx + i);
    if (flags[d.x] == 0) flags[d.x] = 1;
    if (flags[d.y] == 0) flags[d.y] = 1;
    if (flags[d.z] == 0) flags[d.z] = 1;
    if (flags[d.w] == 0) flags[d.w] = 1;
}

__device__ __forceinline__ bf16x8 cvt8(f32x4 lo, f32x4 hi) {
    union { __hip_bfloat16 h[8]; bf16x8 v; } u;
    u.h[0] = __float2bfloat16(lo[0]); u.h[1] = __float2bfloat16(lo[1]);
    u.h[2] = __float2bfloat16(lo[2]); u.h[3] = __float2bfloat16(lo[3]);
    u.h[4] = __float2bfloat16(hi[0]); u.h[5] = __float2bfloat16(hi[1]);
    u.h[6] = __float2bfloat16(hi[2]); u.h[7] = __float2bfloat16(hi[3]);
    return u.v;
}

// ---------- Kernel 3: out[m][n] = flags[m] ? (x @ W)[m][n] : 0 ----------
// R9: BM=224 -> grid 224 <= 256 CUs: kills the 2-block-per-CU tail (R5: 135
// CUs carried 2x1.25 MB while 121 idled) AND cuts B re-reads 100->57 MB.
// BN=256 (x read ONCE), BK=32. 512 thr = 8 waves (2M x 4N), wave 112x64,
// acc[7][4]. Core discipline R7-verbatim (equal-best).
// A staging made THREAD-UNIFORM by padding to 256 rows: thread t -> row t>>1
// (0..255; rows >=224 are dummies reading clamped x[NN-1], L1-hot, written to
// an unread LDS region) -- keeps the vmcnt ledger identical across waves.
// Per thread per step: 4x global_load_dwordx4 f32 (64B), cvt -> 2x bf16x8
// ds_write (async-split: loads for kt+2 issued early, write for kt+1 after
// compute -- HBM latency under the MFMA phase).
// vmcnt ledger (in-order retire; sched_barrier(0) pins issue order; per iter
// queue: [B(kt+1) x2][gA(kt+2) x4]):
//   prologue: gA(0)4, B(0)2, gA(1)4 -> vmcnt(6) retires gA(0)
//   item1 (kt<15): vmcnt(4) lgkm(0) -> retires B(kt); gA(kt+1) flies
//   item5 (kt<14): vmcnt(6) -> retires gA(kt+1); B(kt+1)+gA(kt+2) fly
//   tails: kt=14 item5 vmcnt(2); kt=15 item1 vmcnt(0)
// A LDS: 256 rows x 80 B (64 data + 16 pad), write (r*80+q*32) and frag reads
// both spread 8-ways mod banks -> 2-way (free). B path verbatim R5/R7.
__global__ __launch_bounds__(512, 2) void gemm_mask_kernel(const float* __restrict__ x,
                                                           const __hip_bfloat16* __restrict__ Wt,
                                                           const unsigned char* __restrict__ flags,
                                                           float* __restrict__ out) {
    __shared__ __align__(16) char As[2][20480];   // 256 rows x 80 B, bf16 (rows 224+ dummy)
    __shared__ __align__(16) char Bs[2][16384];

    const int t = threadIdx.x;
    const int w = t >> 6;             // wave 0..7
    const int l = t & 63;
    const int wm = w >> 2;            // 0..1  (M half: rows 0-111 / 112-223)
    const int wn = w & 3;             // 0..3  (N quarter)
    const int m_base = blockIdx.x * 224;

    // ---- A staging: thread -> row ar = t>>1 (0..255), half q = t&1 ----
    // global f32 bytes per step: row slice [kt*128 + q*64, +64)
    const int ar = t >> 1;
    const int q = t & 1;
    const char* aSrcR;
    {
        int m = m_base + ar; if (m > NN - 1) m = NN - 1;   // clamp (stores guarded; rows>=224 dummy)
        aSrcR = (const char*)x + (size_t)m * (KD * 4) + q * 64;
    }
    const int aWr = ar * 80 + q * 32;  // LDS byte dest for this thread's 16 bf16

    // ---- B staging sources (per-lane, inverse-swizzled; verbatim R5/R7) ----
    const char* bSrc[2];
#pragma unroll
    for (int j = 0; j < 2; ++j) {
        int o = j * 8192 + w * 1024 + l * 16;
        int br = o >> 7;
        int g = ((o >> 4) & 7) ^ (br & 7);
        int n = 2 * br + (g >> 2);
        bSrc[j] = (const char*)Wt + (size_t)n * (KD * 2) + (g & 3) * 16;
    }

    // ---- consume-side offsets ----
    const int fr = l & 15;            // fragment row within 16
    const int fo = l >> 4;            // k sub-block 0..3
    // A (bf16, stride 80): row = wm*112 + tm*16 + fr (112%8==0 -> row&7==l&7)
    const int aOff = (wm * 112 + fr) * 80 + fo * 16;
    // B (verbatim R5/R7)
    const int bOff = (wn * 32 + (fr >> 1)) * 128 +
                     (((fr & 1) * 64 + fo * 16) ^ (((fr >> 1) & 7) << 4));

    f32x4 acc[7][4];
#pragma unroll
    for (int i = 0; i < 7; ++i)
#pragma unroll
        for (int j = 0; j < 4; ++j) acc[i][j] = (f32x4){0.f, 0.f, 0.f, 0.f};

    f32x4 ga[2][4];   // gA reg slots; slot kt&1 holds step kt's 16 f32

#define LOAD_GA(kt)                                                                  \
    {                                                                                \
        ga[(kt) & 1][0] = *reinterpret_cast<const f32x4*>(aSrcR + (kt) * 128);       \
        ga[(kt) & 1][1] = *reinterpret_cast<const f32x4*>(aSrcR + (kt) * 128 + 16);  \
        ga[(kt) & 1][2] = *reinterpret_cast<const f32x4*>(aSrcR + (kt) * 128 + 32);  \
        ga[(kt) & 1][3] = *reinterpret_cast<const f32x4*>(aSrcR + (kt) * 128 + 48);  \
    }
#define STAGE_B(kt)                                                  \
    {                                                                \
        GLD16(bSrc[0] + (kt) * 64, &Bs[(kt) & 1][w * 1024]);         \
        GLD16(bSrc[1] + (kt) * 64, &Bs[(kt) & 1][8192 + w * 1024]);  \
    }
#define WRITE_A(kt)                                                          \
    {                                                                        \
        *reinterpret_cast<bf16x8*>(&As[(kt) & 1][aWr]) =                     \
            cvt8(ga[(kt) & 1][0], ga[(kt) & 1][1]);                          \
        *reinterpret_cast<bf16x8*>(&As[(kt) & 1][aWr + 16]) =                \
            cvt8(ga[(kt) & 1][2], ga[(kt) & 1][3]);                          \
    }

    // ---- prologue: queue = [gA(0) x4][B(0) x2][gA(1) x4] ----
    LOAD_GA(0);
    __builtin_amdgcn_sched_barrier(0);
    STAGE_B(0);
    __builtin_amdgcn_sched_barrier(0);
    LOAD_GA(1);
    __builtin_amdgcn_sched_barrier(0);
    asm volatile("s_waitcnt vmcnt(6)" ::: "memory");   // gA(0) landed
    WRITE_A(0);

#pragma unroll
    for (int kt = 0; kt < 16; ++kt) {
        const int cur = kt & 1;
        // item1: B(kt) landed; this wave's ds_writes drained; rendezvous
        if (kt < 15) {
            asm volatile("s_waitcnt vmcnt(4) lgkmcnt(0)" ::: "memory");
        } else {
            asm volatile("s_waitcnt vmcnt(0) lgkmcnt(0)" ::: "memory");
        }
        __builtin_amdgcn_s_barrier();      // LDS A(kt), B(kt) globally ready
        __builtin_amdgcn_sched_barrier(0);

        // item2+3: issue next staging (order pinned: B first, then gA)
        if (kt < 15) STAGE_B(kt + 1);
        __builtin_amdgcn_sched_barrier(0);
        if (kt < 14) LOAD_GA(kt + 2);
        __builtin_amdgcn_sched_barrier(0);

        // item4: compute(kt) -- 28 MFMA
        bf16x8 bfr[4];
#pragma unroll
        for (int tn = 0; tn < 4; ++tn)
            bfr[tn] = *reinterpret_cast<const bf16x8*>(&Bs[cur][bOff + tn * 1024]);
#pragma unroll
        for (int tm = 0; tm < 7; ++tm) {
            bf16x8 afr = *reinterpret_cast<const bf16x8*>(&As[cur][aOff + tm * 1280]);
#pragma unroll
            for (int tn = 0; tn < 4; ++tn)
                acc[tm][tn] = __builtin_amdgcn_mfma_f32_16x16x32_bf16(afr, bfr[tn], acc[tm][tn], 0, 0, 0);
        }

        // item5: gA(kt+1) landed (B(kt+1)+gA(kt+2) stay in flight)
        if (kt < 14) {
            asm volatile("s_waitcnt vmcnt(6)" ::: "memory");
            WRITE_A(kt + 1);
        } else if (kt == 14) {
            asm volatile("s_waitcnt vmcnt(2)" ::: "memory");   // only B(15) in flight
            WRITE_A(15);
        }
    }
#undef LOAD_GA
#undef STAGE_B
#undef WRITE_A

    // ---- epilogue: C/D layout col=lane&15, row=(lane>>4)*4+r ----
    const int col = l & 15;
    const int rq = (l >> 4) * 4;
#pragma unroll
    for (int tm = 0; tm < 7; ++tm) {
#pragma unroll
        for (int r = 0; r < 4; ++r) {
            const int m = m_base + wm * 112 + tm * 16 + rq + r;
            if (m < NN) {
                const float fl = (float)flags[m];
                float* orow = out + (size_t)m * ND + wn * 64 + col;
#pragma unroll
                for (int tn = 0; tn < 4; ++tn)
                    orow[tn * 16] = acc[tm][tn][r] * fl;
            }
        }
    }
}

extern "C" void kernel_launch(void* const* d_in, const int* in_sizes, int n_in,
                              void* d_out, int out_size, void* d_ws, size_t ws_size,
                              hipStream_t stream) {
    const float* x = (const float*)d_in[0];          // (N, 512) f32
    const int* edge_index = (const int*)d_in[1];     // (2, E) i32: row0=src, row1=dst
    const float* W = (const float*)d_in[3];          // (512, 256) f32
    float* out = (float*)d_out;                      // (N, 256) f32

    unsigned char* flags = (unsigned char*)d_ws;                       // NN bytes (16B-aligned)
    __hip_bfloat16* Wt = (__hip_bfloat16*)((char*)d_ws + 65536);       // 256 KB

    prep_kernel<<<45, 256, 0, stream>>>(W, Wt, flags);
    flag_set_kernel<<<(EE / 4 + 255) / 256, 256, 0, stream>>>(edge_index + EE, flags);
    gemm_mask_kernel<<<(NN + 223) / 224, 512, 0, stream>>>(x, Wt, flags, out);
}

// Round 10
// 46.380 us; speedup vs baseline: 1.8449x; 1.0350x over previous
//
#include <hip/hip_runtime.h>
#include <hip/hip_bf16.h>

#define NN 50000      // nodes
#define EE 800000     // edges
#define KD 512        // IN_DIM
#define ND 256        // H*D

typedef __bf16 bf16x8 __attribute__((ext_vector_type(8)));
typedef float f32x4 __attribute__((ext_vector_type(4)));

// fire-and-forget 16B global->LDS copy (dest = wave-uniform base + lane*16)
#define GLD16(g, l) __builtin_amdgcn_global_load_lds( \
    (const __attribute__((address_space(1))) unsigned int*)(g), \
    (__attribute__((address_space(3))) unsigned int*)(l), 16, 0, 0)

// ---------- Kernel 1: fused  (a) W (512x256 f32) -> Wt (256x512 bf16 [n][k])
//                             (b) zero the flags array ----------
__global__ __launch_bounds__(256) void prep_kernel(const float* __restrict__ W,
                                                   __hip_bfloat16* __restrict__ Wt,
                                                   unsigned char* __restrict__ flags) {
    if (blockIdx.x >= 32) {
        int idx = (blockIdx.x - 32) * 256 + threadIdx.x;
        if (idx < 3125) reinterpret_cast<uint4*>(flags)[idx] = (uint4){0, 0, 0, 0};
        return;
    }
    __shared__ __align__(16) __hip_bfloat16 tile[64][72];
    const int bk = blockIdx.x & 7;
    const int bn = blockIdx.x >> 3;
    const int k0 = bk * 64, n0 = bn * 64;
    const int t = threadIdx.x;
    const int r = t >> 2;
    const int c = (t & 3) * 16;
    const float4* src = reinterpret_cast<const float4*>(W + (size_t)(k0 + r) * ND + n0 + c);
#pragma unroll
    for (int i = 0; i < 4; ++i) {
        float4 f = src[i];
        tile[c + i * 4 + 0][r] = __float2bfloat16(f.x);
        tile[c + i * 4 + 1][r] = __float2bfloat16(f.y);
        tile[c + i * 4 + 2][r] = __float2bfloat16(f.z);
        tile[c + i * 4 + 3][r] = __float2bfloat16(f.w);
    }
    __syncthreads();
    uint4* dst = reinterpret_cast<uint4*>(Wt + (size_t)(n0 + r) * KD + k0 + c);
    dst[0] = *reinterpret_cast<const uint4*>(&tile[r][c]);
    dst[1] = *reinterpret_cast<const uint4*>(&tile[r][c + 8]);
}

// ---------- Kernel 2: flags[dst[e]] = 1 via test-and-set ----------
__global__ __launch_bounds__(256) void flag_set_kernel(const int* __restrict__ dst_idx,
                                                       unsigned char* __restrict__ flags) {
    int i = (blockIdx.x * 256 + threadIdx.x) * 4;
    if (i >= EE) return;  // EE % 4 == 0
    int4 d = *reinterpret_cast<const int4*>(dst_idx + i);
    if (flags[d.x] == 0) flags[d.x] = 1;
    if (flags[d.y] == 0) flags[d.y] = 1;
    if (flags[d.z] == 0) flags[d.z] = 1;
    if (flags[d.w] == 0) flags[d.w] = 1;
}

__device__ __forceinline__ bf16x8 cvt8(f32x4 lo, f32x4 hi) {
    union { __hip_bfloat16 h[8]; bf16x8 v; } u;
    u.h[0] = __float2bfloat16(lo[0]); u.h[1] = __float2bfloat16(lo[1]);
    u.h[2] = __float2bfloat16(lo[2]); u.h[3] = __float2bfloat16(lo[3]);
    u.h[4] = __float2bfloat16(hi[0]); u.h[5] = __float2bfloat16(hi[1]);
    u.h[6] = __float2bfloat16(hi[2]); u.h[7] = __float2bfloat16(hi[3]);
    return u.v;
}

// ---------- Kernel 3: out[m][n] = flags[m] ? (x @ W)[m][n] : 0 ----------
// R10: BM=224, grid=224 (balanced, <=256 CUs) x 1024 THREADS = 16 waves/CU
// in one block. Tests the last untested cell: balance + 16-wave concurrency
// (R5: 16 waves unbalanced = 32 GB/s/CU; R9: 8 waves balanced = 22 GB/s/CU).
// 16 waves as 2M x 8N, wave tile 112x32, acc[7][2]. BK=32, 16 steps.
// Discipline is R7-verbatim (async-split A, single barrier per step, counted
// vmcnt). Per thread per step: A = 2x global_load_dwordx4 (32 B f32, rows
// padded to 256, rows>=224 clamped dummies) -> 1 bf16x8 ds_write; B = 1 GLD16.
// vmcnt ledger (queue/iter = [B(kt+1) x1][gA(kt+2) x2]):
//   prologue: gA(0)2, B(0)1, gA(1)2 -> vmcnt(3) retires gA(0)
//   item1: vmcnt(2) retires B(kt) (kt=15: vmcnt(0)); lgkm(0) drains ds_write
//   item5: vmcnt(3) retires gA(kt+1) (kt=14: vmcnt(1))
// Single-barrier WAR: STAGE/WRITE target buf[cur^1], last read at step kt-1;
// every wave passed barrier(kt) after those reads -> safe.
// A LDS: 256 rows x 80 B (64 data + 16 pad): read slots (5*fr+fo)%8 and write
// slots (5*ar+q)%8 uniform -> 2-way (free). B layout verbatim R5/R7.
__global__ __launch_bounds__(1024, 4) void gemm_mask_kernel(const float* __restrict__ x,
                                                            const __hip_bfloat16* __restrict__ Wt,
                                                            const unsigned char* __restrict__ flags,
                                                            float* __restrict__ out) {
    __shared__ __align__(16) char As[2][20480];   // 256 rows x 80 B, bf16 (rows 224+ dummy)
    __shared__ __align__(16) char Bs[2][16384];

    const int t = threadIdx.x;
    const int w = t >> 6;             // wave 0..15
    const int l = t & 63;
    const int wm = w >> 3;            // 0..1  (M half: rows 0-111 / 112-223)
    const int wn = w & 7;             // 0..7  (N eighth: 32 cols)
    const int m_base = blockIdx.x * 224;

    // ---- A staging: thread -> row ar = t>>2 (0..255), quarter q = t&3 ----
    // global f32 bytes per step: row slice [kt*128 + q*32, +32)
    const int ar = t >> 2;
    const int q = t & 3;
    const char* aSrcR;
    {
        int m = m_base + ar; if (m > NN - 1) m = NN - 1;   // clamp (stores guarded; rows>=224 dummy)
        aSrcR = (const char*)x + (size_t)m * (KD * 4) + q * 32;
    }
    const int aWr = ar * 80 + q * 16;  // LDS byte dest for this thread's 8 bf16

    // ---- B staging source (per-lane, inverse-swizzled; 1 GLD16/thread) ----
    // dest byte o = t*16 (0..16383); row br = o>>7 = t>>3; p = (o>>4)&7 = t&7;
    // g = p ^ (br&7); n = 2*br + (g>>2); src = Wt[n] + (g&3)*16 (+kt*64)
    const char* bSrc;
    {
        int br = t >> 3;
        int g = (t & 7) ^ (br & 7);
        int n = 2 * br + (g >> 2);
        bSrc = (const char*)Wt + (size_t)n * (KD * 2) + (g & 3) * 16;
    }

    // ---- consume-side offsets ----
    const int fr = l & 15;            // fragment row within 16
    const int fo = l >> 4;            // k sub-block 0..3
    // A (bf16, stride 80): row = wm*112 + tm*16 + fr
    const int aOff = (wm * 112 + fr) * 80 + fo * 16;
    // B: n = wn*32 + tn*16 + fr ; j = n>>1 = wn*16 + tn*8 + (fr>>1)
    const int bOff = (wn * 16 + (fr >> 1)) * 128 +
                     (((fr & 1) * 64 + fo * 16) ^ (((fr >> 1) & 7) << 4));

    f32x4 acc[7][2];
#pragma unroll
    for (int i = 0; i < 7; ++i)
#pragma unroll
        for (int j = 0; j < 2; ++j) acc[i][j] = (f32x4){0.f, 0.f, 0.f, 0.f};

    f32x4 ga[2][2];   // gA reg slots; slot kt&1 holds step kt's 8 f32

#define LOAD_GA(kt)                                                                  \
    {                                                                                \
        ga[(kt) & 1][0] = *reinterpret_cast<const f32x4*>(aSrcR + (kt) * 128);       \
        ga[(kt) & 1][1] = *reinterpret_cast<const f32x4*>(aSrcR + (kt) * 128 + 16);  \
    }
#define STAGE_B(kt)                                                  \
    GLD16(bSrc + (kt) * 64, &Bs[(kt) & 1][t * 16]);
#define WRITE_A(kt)                                                  \
    *reinterpret_cast<bf16x8*>(&As[(kt) & 1][aWr]) =                 \
        cvt8(ga[(kt) & 1][0], ga[(kt) & 1][1]);

    // ---- prologue: queue = [gA(0) x2][B(0) x1][gA(1) x2] ----
    LOAD_GA(0);
    __builtin_amdgcn_sched_barrier(0);
    STAGE_B(0);
    __builtin_amdgcn_sched_barrier(0);
    LOAD_GA(1);
    __builtin_amdgcn_sched_barrier(0);
    asm volatile("s_waitcnt vmcnt(3)" ::: "memory");   // gA(0) landed
    WRITE_A(0);

#pragma unroll
    for (int kt = 0; kt < 16; ++kt) {
        const int cur = kt & 1;
        // item1: B(kt) landed; this wave's ds_write drained; rendezvous
        if (kt < 15) {
            asm volatile("s_waitcnt vmcnt(2) lgkmcnt(0)" ::: "memory");
        } else {
            asm volatile("s_waitcnt vmcnt(0) lgkmcnt(0)" ::: "memory");
        }
        __builtin_amdgcn_s_barrier();      // LDS A(kt), B(kt) globally ready
        __builtin_amdgcn_sched_barrier(0);

        // item2+3: issue next staging (order pinned: B first, then gA)
        if (kt < 15) STAGE_B(kt + 1);
        __builtin_amdgcn_sched_barrier(0);
        if (kt < 14) LOAD_GA(kt + 2);
        __builtin_amdgcn_sched_barrier(0);

        // item4: compute(kt) -- 14 MFMA
        bf16x8 bfr[2];
#pragma unroll
        for (int tn = 0; tn < 2; ++tn)
            bfr[tn] = *reinterpret_cast<const bf16x8*>(&Bs[cur][bOff + tn * 1024]);
#pragma unroll
        for (int tm = 0; tm < 7; ++tm) {
            bf16x8 afr = *reinterpret_cast<const bf16x8*>(&As[cur][aOff + tm * 1280]);
#pragma unroll
            for (int tn = 0; tn < 2; ++tn)
                acc[tm][tn] = __builtin_amdgcn_mfma_f32_16x16x32_bf16(afr, bfr[tn], acc[tm][tn], 0, 0, 0);
        }

        // item5: gA(kt+1) landed (B(kt+1)+gA(kt+2) stay in flight)
        if (kt < 14) {
            asm volatile("s_waitcnt vmcnt(3)" ::: "memory");
            WRITE_A(kt + 1);
        } else if (kt == 14) {
            asm volatile("s_waitcnt vmcnt(1)" ::: "memory");   // only B(15) in flight
            WRITE_A(15);
        }
    }
#undef LOAD_GA
#undef STAGE_B
#undef WRITE_A

    // ---- epilogue: C/D layout col=lane&15, row=(lane>>4)*4+r ----
    const int col = l & 15;
    const int rq = (l >> 4) * 4;
#pragma unroll
    for (int tm = 0; tm < 7; ++tm) {
#pragma unroll
        for (int r = 0; r < 4; ++r) {
            const int m = m_base + wm * 112 + tm * 16 + rq + r;
            if (m < NN) {
                const float fl = (float)flags[m];
                float* orow = out + (size_t)m * ND + wn * 32 + col;
#pragma unroll
                for (int tn = 0; tn < 2; ++tn)
                    orow[tn * 16] = acc[tm][tn][r] * fl;
            }
        }
    }
}

extern "C" void kernel_launch(void* const* d_in, const int* in_sizes, int n_in,
                              void* d_out, int out_size, void* d_ws, size_t ws_size,
                              hipStream_t stream) {
    const float* x = (const float*)d_in[0];          // (N, 512) f32
    const int* edge_index = (const int*)d_in[1];     // (2, E) i32: row0=src, row1=dst
    const float* W = (const float*)d_in[3];          // (512, 256) f32
    float* out = (float*)d_out;                      // (N, 256) f32

    unsigned char* flags = (unsigned char*)d_ws;                       // NN bytes (16B-aligned)
    __hip_bfloat16* Wt = (__hip_bfloat16*)((char*)d_ws + 65536);       // 256 KB

    prep_kernel<<<45, 256, 0, stream>>>(W, Wt, flags);
    flag_set_kernel<<<(EE / 4 + 255) / 256, 256, 0, stream>>>(edge_index + EE, flags);
    gemm_mask_kernel<<<(NN + 223) / 224, 1024, 0, stream>>>(x, Wt, flags, out);
}

// Round 11
// 44.640 us; speedup vs baseline: 1.9169x; 1.0390x over previous
//
#include <hip/hip_runtime.h>
#include <hip/hip_bf16.h>

#define NN 50000      // nodes
#define EE 800000     // edges
#define KD 512        // IN_DIM
#define ND 256        // H*D

typedef __bf16 bf16x8 __attribute__((ext_vector_type(8)));
typedef float f32x4 __attribute__((ext_vector_type(4)));

// fire-and-forget 16B global->LDS copy (dest = wave-uniform base + lane*16)
#define GLD16(g, l) __builtin_amdgcn_global_load_lds( \
    (const __attribute__((address_space(1))) unsigned int*)(g), \
    (__attribute__((address_space(3))) unsigned int*)(l), 16, 0, 0)

// ---------- Kernel 1: fused  (a) W (512x256 f32) -> Wt (256x512 bf16 [n][k])
//                             (b) zero the flags array ----------
__global__ __launch_bounds__(256) void prep_kernel(const float* __restrict__ W,
                                                   __hip_bfloat16* __restrict__ Wt,
                                                   unsigned char* __restrict__ flags) {
    if (blockIdx.x >= 32) {
        int idx = (blockIdx.x - 32) * 256 + threadIdx.x;
        if (idx < 3125) reinterpret_cast<uint4*>(flags)[idx] = (uint4){0, 0, 0, 0};
        return;
    }
    __shared__ __align__(16) __hip_bfloat16 tile[64][72];
    const int bk = blockIdx.x & 7;
    const int bn = blockIdx.x >> 3;
    const int k0 = bk * 64, n0 = bn * 64;
    const int t = threadIdx.x;
    const int r = t >> 2;
    const int c = (t & 3) * 16;
    const float4* src = reinterpret_cast<const float4*>(W + (size_t)(k0 + r) * ND + n0 + c);
#pragma unroll
    for (int i = 0; i < 4; ++i) {
        float4 f = src[i];
        tile[c + i * 4 + 0][r] = __float2bfloat16(f.x);
        tile[c + i * 4 + 1][r] = __float2bfloat16(f.y);
        tile[c + i * 4 + 2][r] = __float2bfloat16(f.z);
        tile[c + i * 4 + 3][r] = __float2bfloat16(f.w);
    }
    __syncthreads();
    uint4* dst = reinterpret_cast<uint4*>(Wt + (size_t)(n0 + r) * KD + k0 + c);
    dst[0] = *reinterpret_cast<const uint4*>(&tile[r][c]);
    dst[1] = *reinterpret_cast<const uint4*>(&tile[r][c + 8]);
}

// ---------- Kernel 2: flags[dst[e]] = 1 via test-and-set ----------
__global__ __launch_bounds__(256) void flag_set_kernel(const int* __restrict__ dst_idx,
                                                       unsigned char* __restrict__ flags) {
    int i = (blockIdx.x * 256 + threadIdx.x) * 4;
    if (i >= EE) return;  // EE % 4 == 0
    int4 d = *reinterpret_cast<const int4*>(dst_idx + i);
    if (flags[d.x] == 0) flags[d.x] = 1;
    if (flags[d.y] == 0) flags[d.y] = 1;
    if (flags[d.z] == 0) flags[d.z] = 1;
    if (flags[d.w] == 0) flags[d.w] = 1;
}

__device__ __forceinline__ bf16x8 cvt8(f32x4 lo, f32x4 hi) {
    union { __hip_bfloat16 h[8]; bf16x8 v; } u;
    u.h[0] = __float2bfloat16(lo[0]); u.h[1] = __float2bfloat16(lo[1]);
    u.h[2] = __float2bfloat16(lo[2]); u.h[3] = __float2bfloat16(lo[3]);
    u.h[4] = __float2bfloat16(hi[0]); u.h[5] = __float2bfloat16(hi[1]);
    u.h[6] = __float2bfloat16(hi[2]); u.h[7] = __float2bfloat16(hi[2 - 2 + 2]);
    u.h[7] = __float2bfloat16(hi[3]);
    return u.v;
}

// ---------- Kernel 3: out[m][n] = flags[m] ? (x @ W)[m][n] : 0 ----------
// R11 = R5 verbatim (best measured: 44.63 us e2e). BM=128, BN=256 (x read
// ONCE), BK=32. 512 threads = 8 waves (2M x 4N), wave tile 64x64, acc[4][4].
// Double-buffered LDS 64 KB -> 2 blocks/CU = 16 waves/CU as TWO INDEPENDENT
// blocks (the config matrix R5/R9/R10 showed independence is required for the
// ~25 GB/s/CU delivered rate; single-block 16-wave locksteps to ~21).
// Depth-1 counted vmcnt(4), stage-target buffer protected by the previous
// end-of-iter barrier. All staging via GLD16 (survives regalloc; R2/R6's
// register forms collapse to serial loads).
// LDS layouts (linear dest for global_load_lds; swizzle on per-lane GLOBAL
// source + ds_read address -- both-sides, rule 21):
//   A buf 16 KB: row m (0..127) x 128 B (32 f32 of k); phys = log ^ ((m&7)<<4)
//   B buf 16 KB: row j (0..127) x 128 B = n=2j | n=2j+1; phys = log ^ ((j&7)<<4)
__global__ __launch_bounds__(512, 4) void gemm_mask_kernel(const float* __restrict__ x,
                                                           const __hip_bfloat16* __restrict__ Wt,
                                                           const unsigned char* __restrict__ flags,
                                                           float* __restrict__ out) {
    __shared__ __align__(16) char As[2][16384];
    __shared__ __align__(16) char Bs[2][16384];

    const int t = threadIdx.x;
    const int w = t >> 6;             // wave 0..7
    const int l = t & 63;
    const int wm = w >> 2;            // 0..1  (M half)
    const int wn = w & 3;             // 0..3  (N quarter)
    const int m_base = blockIdx.x * 128;

    // ---- staging sources (per-lane, inverse-swizzled) ----
    const char* aSrc[2];
#pragma unroll
    for (int i = 0; i < 2; ++i) {
        int o = i * 8192 + w * 1024 + l * 16;
        int ar = o >> 7;
        int g = ((o >> 4) & 7) ^ (ar & 7);
        int m = m_base + ar; if (m > NN - 1) m = NN - 1;   // clamp (stores guarded)
        aSrc[i] = (const char*)x + (size_t)m * (KD * 4) + g * 16;
    }
    const char* bSrc[2];
#pragma unroll
    for (int i = 0; i < 2; ++i) {
        int o = i * 8192 + w * 1024 + l * 16;
        int br = o >> 7;
        int g = ((o >> 4) & 7) ^ (br & 7);
        int n = 2 * br + (g >> 2);
        bSrc[i] = (const char*)Wt + (size_t)n * (KD * 2) + (g & 3) * 16;
    }

    // ---- consume-side ds_read offsets (swizzled) ----
    const int fr = l & 15;            // fragment row within 16
    const int fo = l >> 4;            // k sub-block 0..3
    const int aOff0 = (wm * 64 + fr) * 128 + ((fo * 32) ^ ((l & 7) << 4));
    const int bOff = (wn * 32 + (fr >> 1)) * 128 +
                     (((fr & 1) * 64 + fo * 16) ^ (((fr >> 1) & 7) << 4));

    f32x4 acc[4][4];
#pragma unroll
    for (int i = 0; i < 4; ++i)
#pragma unroll
        for (int j = 0; j < 4; ++j) acc[i][j] = (f32x4){0.f, 0.f, 0.f, 0.f};

#define STAGE(kt, buf)                                            \
    {                                                             \
        GLD16(aSrc[0] + (kt) * 128, &As[buf][w * 1024]);          \
        GLD16(aSrc[1] + (kt) * 128, &As[buf][8192 + w * 1024]);   \
        GLD16(bSrc[0] + (kt) * 64, &Bs[buf][w * 1024]);           \
        GLD16(bSrc[1] + (kt) * 64, &Bs[buf][8192 + w * 1024]);    \
    }

    // prologue: step 0 in flight (4 loads/wave)
    STAGE(0, 0);

#pragma unroll
    for (int kt = 0; kt < 16; ++kt) {
        const int cur = kt & 1;
        if (kt < 15) {
            STAGE(kt + 1, cur ^ 1);    // target buf last read at kt-1 (end-barrier-protected)
            asm volatile("s_waitcnt vmcnt(4)" ::: "memory");   // step kt landed; 4 stay in flight
        } else {
            asm volatile("s_waitcnt vmcnt(0)" ::: "memory");
        }
        __builtin_amdgcn_s_barrier();      // all waves' step-kt data in LDS
        __builtin_amdgcn_sched_barrier(0); // keep ds_reads below the barrier

        bf16x8 bfr[4];
#pragma unroll
        for (int tn = 0; tn < 4; ++tn)
            bfr[tn] = *reinterpret_cast<const bf16x8*>(&Bs[cur][bOff + tn * 1024]);
        // tm-halves keep live A fragments at 2 (register pressure: acc=64)
#pragma unroll
        for (int h = 0; h < 2; ++h) {
            bf16x8 afr[2];
#pragma unroll
            for (int u = 0; u < 2; ++u) {
                const int p = aOff0 + (h * 2 + u) * 2048;
                f32x4 lo = *reinterpret_cast<const f32x4*>(&As[cur][p]);
                f32x4 hi = *reinterpret_cast<const f32x4*>(&As[cur][p ^ 16]);
                afr[u] = cvt8(lo, hi);
            }
#pragma unroll
            for (int u = 0; u < 2; ++u)
#pragma unroll
                for (int tn = 0; tn < 4; ++tn)
                    acc[h * 2 + u][tn] = __builtin_amdgcn_mfma_f32_16x16x32_bf16(afr[u], bfr[tn], acc[h * 2 + u][tn], 0, 0, 0);
        }

        __builtin_amdgcn_s_barrier();      // all waves done reading buf[cur]
    }
#undef STAGE

    // ---- epilogue: C/D layout col=lane&15, row=(lane>>4)*4+r ----
    const int col = l & 15;
    const int rq = (l >> 4) * 4;
#pragma unroll
    for (int tm = 0; tm < 4; ++tm) {
#pragma unroll
        for (int r = 0; r < 4; ++r) {
            const int m = m_base + wm * 64 + tm * 16 + rq + r;
            if (m < NN) {
                const float fl = (float)flags[m];
                float* orow = out + (size_t)m * ND + wn * 64 + col;
#pragma unroll
                for (int tn = 0; tn < 4; ++tn)
                    orow[tn * 16] = acc[tm][tn][r] * fl;
            }
        }
    }
}

extern "C" void kernel_launch(void* const* d_in, const int* in_sizes, int n_in,
                              void* d_out, int out_size, void* d_ws, size_t ws_size,
                              hipStream_t stream) {
    const float* x = (const float*)d_in[0];          // (N, 512) f32
    const int* edge_index = (const int*)d_in[1];     // (2, E) i32: row0=src, row1=dst
    const float* W = (const float*)d_in[3];          // (512, 256) f32
    float* out = (float*)d_out;                      // (N, 256) f32

    unsigned char* flags = (unsigned char*)d_ws;                       // NN bytes (16B-aligned)
    __hip_bfloat16* Wt = (__hip_bfloat16*)((char*)d_ws + 65536);       // 256 KB

    prep_kernel<<<45, 256, 0, stream>>>(W, Wt, flags);
    flag_set_kernel<<<(EE / 4 + 255) / 256, 256, 0, stream>>>(edge_index + EE, flags);
    gemm_mask_kernel<<<(NN + 127) / 128, 512, 0, stream>>>(x, Wt, flags, out);
}